// Round 12
// baseline (308.579 us; speedup 1.0000x reference)
//
#include <hip/hip_runtime.h>

// EncoderBlock on MI355X. Round 12: register-prefetch software pipelining in all
// GEMM staging loops (attn-style; hides global->LDS latency at 1 block/CU).
// 6 launches. Inputs fp32 storage, d_out fp32. B=16 T=1024 C=256 H=8 D=32.

typedef unsigned short u16;
typedef unsigned int u32;
typedef __attribute__((ext_vector_type(8))) short short8v;  // 8 bf16 MFMA A/B frag
typedef __attribute__((ext_vector_type(4))) float float4v;  // MFMA C/D frag

__device__ __forceinline__ float b2f(u16 u) { union { u32 i; float f; } v; v.i = (u32)u << 16; return v.f; }
__device__ __forceinline__ float lo2f(u32 u) { union { u32 i; float f; } v; v.i = u << 16; return v.f; }
__device__ __forceinline__ float hi2f(u32 u) { union { u32 i; float f; } v; v.i = u & 0xffff0000u; return v.f; }
__device__ __forceinline__ u16 f2b(float f) {
    union { float f; u32 i; } v; v.f = f;
    u32 r = v.i + 0x7fffu + ((v.i >> 16) & 1u);  // RTNE
    return (u16)(r >> 16);
}
__device__ __forceinline__ u32 pk2_rtz(float a, float b) {
    return (__float_as_uint(a) >> 16) | (__float_as_uint(b) & 0xffff0000u);
}

// ---------------- fused prep (wqkv pack + 3 transposes) + LN1 ---------------
__global__ __launch_bounds__(256) void prep_ln1(const float* __restrict__ wq,
                                                const float* __restrict__ wk,
                                                const float* __restrict__ wv,
                                                const float* __restrict__ wp,
                                                const float* __restrict__ w1,
                                                const float* __restrict__ w2,
                                                const float* __restrict__ x,
                                                const float* __restrict__ g1,
                                                const float* __restrict__ be1,
                                                u16* __restrict__ wqkvT,
                                                u16* __restrict__ wpT,
                                                u16* __restrict__ w1T,
                                                u16* __restrict__ w2T,
                                                u16* __restrict__ hout) {
    __shared__ u16 tile[64][65];
    int bid = blockIdx.x, tid = threadIdx.x;
    if (bid < 768) {
        int i = bid * 256 + tid;
        int n = i >> 8, k = i & 255;
        int which = n >> 8, nn = n & 255;
        const float* w = which == 0 ? wq : (which == 1 ? wk : wv);
        float v = w[((nn >> 5) * 256 + k) * 32 + (nn & 31)];   // w[h][k][d]
        if (which == 0) v *= 0.09016844f;                      // (1/16)*log2(e)
        wqkvT[i] = f2b(v);
    } else if (bid < 912) {
        const float* src; u16* dst; int K, N, t;
        if (bid < 784)      { src = wp; dst = wpT; K = 256;  N = 256;  t = bid - 768; }
        else if (bid < 848) { src = w1; dst = w1T; K = 256;  N = 1024; t = bid - 784; }
        else                { src = w2; dst = w2T; K = 1024; N = 256;  t = bid - 848; }
        int ntn = N >> 6;
        int k0 = (t / ntn) << 6, n0 = (t % ntn) << 6;
        int lane = tid & 63, wrow = tid >> 6;
        #pragma unroll
        for (int r = 0; r < 16; r++) {
            int k = wrow * 16 + r;
            tile[k][lane] = f2b(src[(size_t)(k0 + k) * N + n0 + lane]);
        }
        __syncthreads();
        #pragma unroll
        for (int r = 0; r < 16; r++) {
            int n = wrow * 16 + r;
            dst[(size_t)(n0 + n) * K + k0 + lane] = tile[lane][n];
        }
    } else {
        int row = (bid - 912) * 4 + (tid >> 6);
        int lane = tid & 63;
        float4 xv = *(const float4*)(x + (size_t)row * 256 + lane * 4);
        float v0 = xv.x, v1 = xv.y, v2 = xv.z, v3 = xv.w;
        float s = v0 + v1 + v2 + v3;
        #pragma unroll
        for (int m = 32; m; m >>= 1) s += __shfl_xor(s, m);
        float mu = s * 0.00390625f;
        float d0 = v0 - mu, d1 = v1 - mu, d2 = v2 - mu, d3 = v3 - mu;
        float ss = d0 * d0 + d1 * d1 + d2 * d2 + d3 * d3;
        #pragma unroll
        for (int m = 32; m; m >>= 1) ss += __shfl_xor(ss, m);
        float rs = rsqrtf(ss * 0.00390625f + 1e-5f);
        float4 g = *(const float4*)(g1 + lane * 4);
        float4 b = *(const float4*)(be1 + lane * 4);
        uint2 r;
        r.x = (u32)f2b(d0 * rs * g.x + b.x) | ((u32)f2b(d1 * rs * g.y + b.y) << 16);
        r.y = (u32)f2b(d2 * rs * g.z + b.z) | ((u32)f2b(d3 * rs * g.w + b.w) << 16);
        *(uint2*)(hout + (size_t)row * 256 + lane * 4) = r;
    }
}

// ---------------- 128x128 MFMA GEMM, register-prefetch pipelined ------------
// C[M,N] = A[M,K] @ Bt[N,K]^T. D rows = n, cols = m. Staging: per-lane uint4
// loads into regs; loop: barrier -> regs->LDS -> barrier -> prefetch next ->
// compute. LDS write addr = lane*16B (contiguous; identical layout to the
// async_cp16 version, XOR k-chunk swizzle on the global side).
// QKV: n0>=512 -> V transposed scatter into vout; out = [BT,512] q|k.
template<bool HASBIAS, bool RELU, int RES, bool OUT32, bool QKV>
__global__ __launch_bounds__(256) void gemm128(const u16* __restrict__ A,
                                               const u16* __restrict__ Bt,
                                               const float* __restrict__ bias,
                                               const void* __restrict__ resid,
                                               void* __restrict__ out,
                                               u16* __restrict__ vout,
                                               int M, int N, int K) {
    __shared__ __align__(16) u16 As[128 * 64];
    __shared__ __align__(16) u16 Bs[128 * 64];
    const int tid = threadIdx.x, lane = tid & 63, w = tid >> 6;
    const int m0 = blockIdx.x * 128, n0 = blockIdx.y * 128;
    const int wm = (w & 1) * 64, wn = (w >> 1) * 64;
    const int fm = lane & 15, q = lane >> 4;

    float4v acc[4][4];
    #pragma unroll
    for (int i = 0; i < 4; i++)
        #pragma unroll
        for (int j = 0; j < 4; j++) acc[i][j] = (float4v){0.f, 0.f, 0.f, 0.f};

    const int kset = ((lane & 7) ^ (lane >> 3)) * 8;
    const u16* Ag = A  + (size_t)(m0 + w * 32 + (lane >> 3)) * K + kset;
    const u16* Bg = Bt + (size_t)(n0 + w * 32 + (lane >> 3)) * K + kset;
    u16* Awr = As + (w * 32) * 64 + lane * 8;    // == async lane-order placement
    u16* Bwr = Bs + (w * 32) * 64 + lane * 8;

    uint4 aR[4], bR[4];
    #pragma unroll
    for (int c = 0; c < 4; c++) {
        aR[c] = *(const uint4*)(Ag + (size_t)c * 8 * K);
        bR[c] = *(const uint4*)(Bg + (size_t)c * 8 * K);
    }

    const int sw = fm & 7;
    for (int k0 = 0; k0 < K; k0 += 64) {
        __syncthreads();                         // prior compute done with LDS
        #pragma unroll
        for (int c = 0; c < 4; c++) {
            *(uint4*)(Awr + c * 8 * 64) = aR[c];
            *(uint4*)(Bwr + c * 8 * 64) = bR[c];
        }
        __syncthreads();
        if (k0 + 64 < K) {                       // prefetch next k-tile
            #pragma unroll
            for (int c = 0; c < 4; c++) {
                aR[c] = *(const uint4*)(Ag + (size_t)c * 8 * K + k0 + 64);
                bR[c] = *(const uint4*)(Bg + (size_t)c * 8 * K + k0 + 64);
            }
        }
        #pragma unroll
        for (int kk = 0; kk < 64; kk += 32) {
            const int slot = (((kk >> 3) + q) ^ sw) * 8;
            short8v af[4], bf[4];
            #pragma unroll
            for (int mi = 0; mi < 4; mi++)
                af[mi] = *(const short8v*)&As[(wm + mi * 16 + fm) * 64 + slot];
            #pragma unroll
            for (int ni = 0; ni < 4; ni++)
                bf[ni] = *(const short8v*)&Bs[(wn + ni * 16 + fm) * 64 + slot];
            #pragma unroll
            for (int mi = 0; mi < 4; mi++)
                #pragma unroll
                for (int ni = 0; ni < 4; ni++)
                    acc[mi][ni] = __builtin_amdgcn_mfma_f32_16x16x32_bf16(
                        bf[ni], af[mi], acc[mi][ni], 0, 0, 0);
        }
    }

    #pragma unroll
    for (int mi = 0; mi < 4; mi++) {
        int row = m0 + wm + mi * 16 + fm;
        #pragma unroll
        for (int ni = 0; ni < 4; ni++) {
            int nb = n0 + wn + ni * 16 + q * 4;
            float v0 = acc[mi][ni][0], v1 = acc[mi][ni][1],
                  v2 = acc[mi][ni][2], v3 = acc[mi][ni][3];
            if (HASBIAS) {
                float4 bv = *(const float4*)&bias[nb];
                v0 += bv.x; v1 += bv.y; v2 += bv.z; v3 += bv.w;
            }
            if (RELU) {
                v0 = fmaxf(v0, 0.f); v1 = fmaxf(v1, 0.f);
                v2 = fmaxf(v2, 0.f); v3 = fmaxf(v3, 0.f);
            }
            if (QKV && n0 >= 512) {
                int hd = nb - 512;
                int vr = ((row >> 10) * 8 + (hd >> 5)) * 32 + (hd & 31);
                int tl = row & 1023;
                vout[(size_t)(vr + 0) * 1024 + tl] = f2b(v0);
                vout[(size_t)(vr + 1) * 1024 + tl] = f2b(v1);
                vout[(size_t)(vr + 2) * 1024 + tl] = f2b(v2);
                vout[(size_t)(vr + 3) * 1024 + tl] = f2b(v3);
            } else {
                size_t idx = (size_t)row * N + nb;
                if (RES == 1) {
                    uint2 rv = *(const uint2*)&((const u16*)resid)[idx];
                    v0 += lo2f(rv.x); v1 += hi2f(rv.x);
                    v2 += lo2f(rv.y); v3 += hi2f(rv.y);
                }
                if (OUT32) {
                    *(float4*)&((float*)out)[idx] = (float4){v0, v1, v2, v3};
                } else {
                    uint2 ov;
                    ov.x = (u32)f2b(v0) | ((u32)f2b(v1) << 16);
                    ov.y = (u32)f2b(v2) | ((u32)f2b(v3) << 16);
                    *(uint2*)&((u16*)out)[idx] = ov;
                }
            }
        }
    }
}

// ---------------- proj GEMM + residual + LN2, pipelined ---------------------
// x2 = att @ wpT^T + b_proj + x ; h2 = LN2(x2). 64 rows x 256 cols per block;
// wave owns 16 full rows -> stats via quad shuffles. h2 in-place over att.
__global__ __launch_bounds__(256) void proj_ln2(const u16* __restrict__ att,
                                                const u16* __restrict__ wpT,
                                                const float* __restrict__ bp,
                                                const float* __restrict__ x,
                                                const float* __restrict__ g2,
                                                const float* __restrict__ be2,
                                                u16* __restrict__ x2b,
                                                u16* __restrict__ h2) {
    __shared__ __align__(16) u16 As[64 * 64];
    __shared__ __align__(16) u16 Bs[256 * 64];
    __shared__ float gs[256], bs[256], bps[256];
    const int tid = threadIdx.x, lane = tid & 63, w = tid >> 6;
    const int m0 = blockIdx.x * 64;
    const int fm = lane & 15, q = lane >> 4;

    gs[tid] = g2[tid]; bs[tid] = be2[tid]; bps[tid] = bp[tid];

    float4v acc[16];
    #pragma unroll
    for (int i = 0; i < 16; i++) acc[i] = (float4v){0.f, 0.f, 0.f, 0.f};

    const int kset = ((lane & 7) ^ (lane >> 3)) * 8;
    const u16* Ag = att + (size_t)(m0 + w * 16 + (lane >> 3)) * 256 + kset;
    const u16* Bg = wpT + (size_t)(w * 64 + (lane >> 3)) * 256 + kset;
    u16* Awr = As + (w * 16) * 64 + lane * 8;
    u16* Bwr = Bs + (w * 64) * 64 + lane * 8;

    uint4 aR[2], bR[8];
    #pragma unroll
    for (int c = 0; c < 2; c++) aR[c] = *(const uint4*)(Ag + (size_t)c * 8 * 256);
    #pragma unroll
    for (int c = 0; c < 8; c++) bR[c] = *(const uint4*)(Bg + (size_t)c * 8 * 256);

    const int sw = fm & 7;
    for (int k0 = 0; k0 < 256; k0 += 64) {
        __syncthreads();
        #pragma unroll
        for (int c = 0; c < 2; c++) *(uint4*)(Awr + c * 8 * 64) = aR[c];
        #pragma unroll
        for (int c = 0; c < 8; c++) *(uint4*)(Bwr + c * 8 * 64) = bR[c];
        __syncthreads();
        if (k0 + 64 < 256) {
            #pragma unroll
            for (int c = 0; c < 2; c++)
                aR[c] = *(const uint4*)(Ag + (size_t)c * 8 * 256 + k0 + 64);
            #pragma unroll
            for (int c = 0; c < 8; c++)
                bR[c] = *(const uint4*)(Bg + (size_t)c * 8 * 256 + k0 + 64);
        }
        #pragma unroll
        for (int kk = 0; kk < 64; kk += 32) {
            const int slot = (((kk >> 3) + q) ^ sw) * 8;
            short8v af = *(const short8v*)&As[(w * 16 + fm) * 64 + slot];
            #pragma unroll
            for (int ni = 0; ni < 16; ni++) {
                short8v bf = *(const short8v*)&Bs[(ni * 16 + fm) * 64 + slot];
                acc[ni] = __builtin_amdgcn_mfma_f32_16x16x32_bf16(bf, af, acc[ni], 0, 0, 0);
            }
        }
    }

    int m = m0 + w * 16 + fm;
    float v[16][4];
    float s = 0.f, sq = 0.f;
    #pragma unroll
    for (int ni = 0; ni < 16; ni++) {
        int nb = ni * 16 + q * 4;
        float4 xv = *(const float4*)(x + (size_t)m * 256 + nb);
        float4 bv = *(const float4*)&bps[nb];
        #pragma unroll
        for (int r = 0; r < 4; r++) {
            float t = acc[ni][r] + (&bv.x)[r] + (&xv.x)[r];
            v[ni][r] = t;
            s += t; sq += t * t;
        }
    }
    s += __shfl_xor(s, 16);  s += __shfl_xor(s, 32);
    sq += __shfl_xor(sq, 16); sq += __shfl_xor(sq, 32);
    float mu = s * 0.00390625f;
    float rs = rsqrtf(sq * 0.00390625f - mu * mu + 1e-5f);
    #pragma unroll
    for (int ni = 0; ni < 16; ni++) {
        int nb = ni * 16 + q * 4;
        size_t idx = (size_t)m * 256 + nb;
        float4 gv = *(const float4*)&gs[nb];
        float4 bv = *(const float4*)&bs[nb];
        uint2 xo, ho;
        xo.x = (u32)f2b(v[ni][0]) | ((u32)f2b(v[ni][1]) << 16);
        xo.y = (u32)f2b(v[ni][2]) | ((u32)f2b(v[ni][3]) << 16);
        float h0 = (v[ni][0] - mu) * rs * gv.x + bv.x;
        float h1 = (v[ni][1] - mu) * rs * gv.y + bv.y;
        float h2v = (v[ni][2] - mu) * rs * gv.z + bv.z;
        float h3 = (v[ni][3] - mu) * rs * gv.w + bv.w;
        ho.x = (u32)f2b(h0) | ((u32)f2b(h1) << 16);
        ho.y = (u32)f2b(h2v) | ((u32)f2b(h3) << 16);
        *(uint2*)&x2b[idx] = xo;
        *(uint2*)&h2[idx] = ho;    // in-place over att: own rows, post-k-loop
    }
}

// ---------------- MFMA flash attention: single sweep, dual q-tile -----------
__global__ __launch_bounds__(256) void attn_mfma(const u16* __restrict__ qk,
                                                 const u16* __restrict__ vtg,
                                                 u16* __restrict__ att) {
    const int T = 1024;
    int jj = (blockIdx.x + (blockIdx.y >> 3)) & 7;
    int b = blockIdx.y >> 3, hh = blockIdx.y & 7;
    int tid = threadIdx.x;
    int lane = tid & 63, w = tid >> 6;
    int fm = lane & 15, q = lane >> 4;

    __shared__ __align__(16) u16 Ks[64][72];
    __shared__ __align__(16) u16 Vt[32][72];
    __shared__ __align__(16) u16 Pl[4][16][72];

    size_t base = (size_t)b * T * 512;
    const u16* kb = qk + base + 256 + hh * 32;
    const u16* vt = vtg + (size_t)((b * 8 + hh) * 32) * 1024;
    const int krow = tid >> 2, kcol = (tid & 3) * 8;
    const int vd = tid >> 3, vs = (tid & 7) * 8;

    int qa0 = jj * 64, qb0 = (15 - jj) * 64;
    int tqa = qa0 + w * 16 + fm, tqb = qb0 + w * 16 + fm;
    short8v qfa = *(const short8v*)(qk + base + (size_t)tqa * 512 + hh * 32 + q * 8);
    short8v qfb = *(const short8v*)(qk + base + (size_t)tqb * 512 + hh * 32 + q * 8);
    float4v oa0 = {0.f, 0.f, 0.f, 0.f}, oa1 = {0.f, 0.f, 0.f, 0.f};
    float4v ob0 = {0.f, 0.f, 0.f, 0.f}, ob1 = {0.f, 0.f, 0.f, 0.f};
    float la = 0.f, lb = 0.f;
    int wqa = qa0 + w * 16, wqb = qb0 + w * 16;
    int nIter = 16 - jj;

    uint4 kreg = *(const uint4*)(kb + (size_t)krow * 512 + kcol);
    uint4 vreg = *(const uint4*)(vt + (size_t)vd * 1024 + vs);

    for (int it = 0; it < nIter; ++it) {
        int s0 = it << 6;
        __syncthreads();
        *(uint4*)&Ks[krow][kcol] = kreg;
        *(uint4*)&Vt[vd][vs] = vreg;
        __syncthreads();
        if (it + 1 < nIter) {
            int ns0 = s0 + 64;
            kreg = *(const uint4*)(kb + (size_t)(ns0 + krow) * 512 + kcol);
            vreg = *(const uint4*)(vt + (size_t)vd * 1024 + ns0 + vs);
        }
        short8v kf0 = *(const short8v*)&Ks[fm][q * 8];
        short8v kf1 = *(const short8v*)&Ks[16 + fm][q * 8];
        short8v kf2 = *(const short8v*)&Ks[32 + fm][q * 8];
        short8v kf3 = *(const short8v*)&Ks[48 + fm][q * 8];
        short8v vf00 = *(const short8v*)&Vt[fm][q * 8];
        short8v vf01 = *(const short8v*)&Vt[fm][32 + q * 8];
        short8v vf10 = *(const short8v*)&Vt[16 + fm][q * 8];
        short8v vf11 = *(const short8v*)&Vt[16 + fm][32 + q * 8];
        float4v z = {0.f, 0.f, 0.f, 0.f};

        #pragma unroll
        for (int t2 = 0; t2 < 2; t2++) {       // t2=0: tile b (large), 1: tile a
            int wq0 = t2 ? wqa : wqb;
            if (s0 >= wq0 + 16) continue;      // wave-uniform causal skip
            int tq = t2 ? tqa : tqb;
            short8v qf = t2 ? qfa : qfb;
            float4v s_0 = __builtin_amdgcn_mfma_f32_16x16x32_bf16(kf0, qf, z, 0, 0, 0);
            float4v s_1 = __builtin_amdgcn_mfma_f32_16x16x32_bf16(kf1, qf, z, 0, 0, 0);
            float4v s_2 = __builtin_amdgcn_mfma_f32_16x16x32_bf16(kf2, qf, z, 0, 0, 0);
            float4v s_3 = __builtin_amdgcn_mfma_f32_16x16x32_bf16(kf3, qf, z, 0, 0, 0);
            float p[16];
            #pragma unroll
            for (int r = 0; r < 4; r++) {
                p[r] = exp2f(s_0[r]); p[4 + r] = exp2f(s_1[r]);
                p[8 + r] = exp2f(s_2[r]); p[12 + r] = exp2f(s_3[r]);
            }
            if (s0 + 63 > wq0) {               // diagonal region: causal mask
                int sb = s0 + q * 4;
                #pragma unroll
                for (int c = 0; c < 4; c++)
                    #pragma unroll
                    for (int r = 0; r < 4; r++)
                        if (sb + c * 16 + r > tq) p[c * 4 + r] = 0.f;
            }
            float rsum = 0.f;
            #pragma unroll
            for (int i = 0; i < 16; i++) rsum += p[i];
            rsum += __shfl_xor(rsum, 16);
            rsum += __shfl_xor(rsum, 32);
            if (t2) la += rsum; else lb += rsum;

            #pragma unroll
            for (int c = 0; c < 4; c++) {
                uint2 pp;
                pp.x = pk2_rtz(p[c * 4 + 0], p[c * 4 + 1]);
                pp.y = pk2_rtz(p[c * 4 + 2], p[c * 4 + 3]);
                *(uint2*)&Pl[w][fm][c * 16 + q * 4] = pp;   // wave-internal
            }
            short8v pf0 = *(const short8v*)&Pl[w][fm][q * 8];
            short8v pf1 = *(const short8v*)&Pl[w][fm][32 + q * 8];
            if (t2) {
                oa0 = __builtin_amdgcn_mfma_f32_16x16x32_bf16(vf00, pf0, oa0, 0, 0, 0);
                oa0 = __builtin_amdgcn_mfma_f32_16x16x32_bf16(vf01, pf1, oa0, 0, 0, 0);
                oa1 = __builtin_amdgcn_mfma_f32_16x16x32_bf16(vf10, pf0, oa1, 0, 0, 0);
                oa1 = __builtin_amdgcn_mfma_f32_16x16x32_bf16(vf11, pf1, oa1, 0, 0, 0);
            } else {
                ob0 = __builtin_amdgcn_mfma_f32_16x16x32_bf16(vf00, pf0, ob0, 0, 0, 0);
                ob0 = __builtin_amdgcn_mfma_f32_16x16x32_bf16(vf01, pf1, ob0, 0, 0, 0);
                ob1 = __builtin_amdgcn_mfma_f32_16x16x32_bf16(vf10, pf0, ob1, 0, 0, 0);
                ob1 = __builtin_amdgcn_mfma_f32_16x16x32_bf16(vf11, pf1, ob1, 0, 0, 0);
            }
        }
    }

    #pragma unroll
    for (int t2 = 0; t2 < 2; t2++) {
        float inv = 1.f / (t2 ? la : lb);
        float4v o0 = t2 ? oa0 : ob0, o1 = t2 ? oa1 : ob1;
        int tq = t2 ? tqa : tqb;
        uint2 r0, r1;
        r0.x = (u32)f2b(o0[0] * inv) | ((u32)f2b(o0[1] * inv) << 16);
        r0.y = (u32)f2b(o0[2] * inv) | ((u32)f2b(o0[3] * inv) << 16);
        r1.x = (u32)f2b(o1[0] * inv) | ((u32)f2b(o1[1] * inv) << 16);
        r1.y = (u32)f2b(o1[2] * inv) | ((u32)f2b(o1[3] * inv) << 16);
        size_t o = (size_t)(b * T + tq) * 256 + hh * 32;
        *(uint2*)(att + o + q * 4) = r0;
        *(uint2*)(att + o + 16 + q * 4) = r1;
    }
}

// ---------------- launch ----------------
extern "C" void kernel_launch(void* const* d_in, const int* in_sizes, int n_in,
                              void* d_out, int out_size, void* d_ws, size_t ws_size,
                              hipStream_t stream) {
    const int BT = 16 * 1024;
    const float* x      = (const float*)d_in[0];
    const float* wq     = (const float*)d_in[1];
    const float* wk     = (const float*)d_in[2];
    const float* wv     = (const float*)d_in[3];
    const float* w_proj = (const float*)d_in[4];
    const float* b_proj = (const float*)d_in[5];
    const float* w1     = (const float*)d_in[6];
    const float* b1     = (const float*)d_in[7];
    const float* w2     = (const float*)d_in[8];
    const float* b2     = (const float*)d_in[9];
    const float* ln1_g  = (const float*)d_in[10];
    const float* ln1_b  = (const float*)d_in[11];
    const float* ln2_g  = (const float*)d_in[12];
    const float* ln2_b  = (const float*)d_in[13];

    // Workspace (~49.5 MiB):
    //   [0, 8M)   x2b (bf16 x2)
    //   [8M,16M)  hbuf: h -> att -> h2  [serial, proj_ln2 in-place]
    //   [16M,32M) qk  [BT,512] | [32M,48M) vtg  -> dead after attn
    //   [16M,48M) mid (born after attn)
    //   [48M...)  packed weights (1.5M)
    char* ws = (char*)d_ws;
    const size_t MB = 1024 * 1024;
    u16*  x2b   = (u16*)(ws + 0);
    u16*  hbuf  = (u16*)(ws + 8 * MB);
    u16*  qk    = (u16*)(ws + 16 * MB);
    u16*  vtg   = (u16*)(ws + 32 * MB);
    u16*  mid   = (u16*)(ws + 16 * MB);
    u16*  wqkvT = (u16*)(ws + 48 * MB);
    u16*  wpT   = (u16*)(ws + 48 * MB + 0x60000);
    u16*  w1T   = (u16*)(ws + 48 * MB + 0x80000);
    u16*  w2T   = (u16*)(ws + 48 * MB + 0x100000);

    prep_ln1<<<5008, 256, 0, stream>>>(wq, wk, wv, w_proj, w1, w2, x, ln1_g, ln1_b,
                                       wqkvT, wpT, w1T, w2T, hbuf);
    gemm128<false, false, 0, false, true><<<dim3(128, 6), 256, 0, stream>>>(
        hbuf, wqkvT, nullptr, nullptr, qk, vtg, BT, 512, 256);
    attn_mfma<<<dim3(8, 128), 256, 0, stream>>>(qk, vtg, hbuf);
    proj_ln2<<<256, 256, 0, stream>>>(hbuf, wpT, b_proj, x, ln2_g, ln2_b, x2b, hbuf);
    gemm128<true, true, 0, false, false><<<dim3(128, 8), 256, 0, stream>>>(
        hbuf, w1T, b1, nullptr, mid, nullptr, BT, 1024, 256);
    gemm128<true, false, 1, true, false><<<dim3(128, 2), 256, 0, stream>>>(
        mid, w2T, b2, x2b, d_out, nullptr, BT, 256, 1024);
}

// Round 13
// 198.038 us; speedup vs baseline: 1.5582x; 1.5582x over previous
//
#include <hip/hip_runtime.h>

// EncoderBlock on MI355X. Round 13: revert r12 pipelining (async global_load_lds
// staging restored everywhere — r12 proved VGPR round-trip staging regresses);
// V-transpose epilogue now goes through LDS -> coalesced 128B-line stores
// (r12 counters: V scalar scatter caused 127MB WRITE_SIZE vs 32MB ideal).
// 6 launches. Inputs fp32 storage, d_out fp32. B=16 T=1024 C=256 H=8 D=32.

typedef unsigned short u16;
typedef unsigned int u32;
typedef __attribute__((ext_vector_type(8))) short short8v;  // 8 bf16 MFMA A/B frag
typedef __attribute__((ext_vector_type(4))) float float4v;  // MFMA C/D frag

__device__ __forceinline__ float b2f(u16 u) { union { u32 i; float f; } v; v.i = (u32)u << 16; return v.f; }
__device__ __forceinline__ float lo2f(u32 u) { union { u32 i; float f; } v; v.i = u << 16; return v.f; }
__device__ __forceinline__ float hi2f(u32 u) { union { u32 i; float f; } v; v.i = u & 0xffff0000u; return v.f; }
__device__ __forceinline__ u16 f2b(float f) {
    union { float f; u32 i; } v; v.f = f;
    u32 r = v.i + 0x7fffu + ((v.i >> 16) & 1u);  // RTNE
    return (u16)(r >> 16);
}
__device__ __forceinline__ u32 pk2_rtz(float a, float b) {
    return (__float_as_uint(a) >> 16) | (__float_as_uint(b) & 0xffff0000u);
}
__device__ __forceinline__ void async_cp16(const u16* g, u16* l) {
    __builtin_amdgcn_global_load_lds((const __attribute__((address_space(1))) void*)g,
                                     (__attribute__((address_space(3))) void*)l, 16, 0, 0);
}

// ---------------- fused prep (wqkv pack + 3 transposes) + LN1 ---------------
__global__ __launch_bounds__(256) void prep_ln1(const float* __restrict__ wq,
                                                const float* __restrict__ wk,
                                                const float* __restrict__ wv,
                                                const float* __restrict__ wp,
                                                const float* __restrict__ w1,
                                                const float* __restrict__ w2,
                                                const float* __restrict__ x,
                                                const float* __restrict__ g1,
                                                const float* __restrict__ be1,
                                                u16* __restrict__ wqkvT,
                                                u16* __restrict__ wpT,
                                                u16* __restrict__ w1T,
                                                u16* __restrict__ w2T,
                                                u16* __restrict__ hout) {
    __shared__ u16 tile[64][65];
    int bid = blockIdx.x, tid = threadIdx.x;
    if (bid < 768) {
        int i = bid * 256 + tid;
        int n = i >> 8, k = i & 255;
        int which = n >> 8, nn = n & 255;
        const float* w = which == 0 ? wq : (which == 1 ? wk : wv);
        float v = w[((nn >> 5) * 256 + k) * 32 + (nn & 31)];   // w[h][k][d]
        if (which == 0) v *= 0.09016844f;                      // (1/16)*log2(e)
        wqkvT[i] = f2b(v);
    } else if (bid < 912) {
        const float* src; u16* dst; int K, N, t;
        if (bid < 784)      { src = wp; dst = wpT; K = 256;  N = 256;  t = bid - 768; }
        else if (bid < 848) { src = w1; dst = w1T; K = 256;  N = 1024; t = bid - 784; }
        else                { src = w2; dst = w2T; K = 1024; N = 256;  t = bid - 848; }
        int ntn = N >> 6;
        int k0 = (t / ntn) << 6, n0 = (t % ntn) << 6;
        int lane = tid & 63, wrow = tid >> 6;
        #pragma unroll
        for (int r = 0; r < 16; r++) {
            int k = wrow * 16 + r;
            tile[k][lane] = f2b(src[(size_t)(k0 + k) * N + n0 + lane]);
        }
        __syncthreads();
        #pragma unroll
        for (int r = 0; r < 16; r++) {
            int n = wrow * 16 + r;
            dst[(size_t)(n0 + n) * K + k0 + lane] = tile[lane][n];
        }
    } else {
        int row = (bid - 912) * 4 + (tid >> 6);
        int lane = tid & 63;
        float4 xv = *(const float4*)(x + (size_t)row * 256 + lane * 4);
        float v0 = xv.x, v1 = xv.y, v2 = xv.z, v3 = xv.w;
        float s = v0 + v1 + v2 + v3;
        #pragma unroll
        for (int m = 32; m; m >>= 1) s += __shfl_xor(s, m);
        float mu = s * 0.00390625f;
        float d0 = v0 - mu, d1 = v1 - mu, d2 = v2 - mu, d3 = v3 - mu;
        float ss = d0 * d0 + d1 * d1 + d2 * d2 + d3 * d3;
        #pragma unroll
        for (int m = 32; m; m >>= 1) ss += __shfl_xor(ss, m);
        float rs = rsqrtf(ss * 0.00390625f + 1e-5f);
        float4 g = *(const float4*)(g1 + lane * 4);
        float4 b = *(const float4*)(be1 + lane * 4);
        uint2 r;
        r.x = (u32)f2b(d0 * rs * g.x + b.x) | ((u32)f2b(d1 * rs * g.y + b.y) << 16);
        r.y = (u32)f2b(d2 * rs * g.z + b.z) | ((u32)f2b(d3 * rs * g.w + b.w) << 16);
        *(uint2*)(hout + (size_t)row * 256 + lane * 4) = r;
    }
}

// ---------------- 128x128 MFMA GEMM, async staging (r11) + LDS V-transpose --
// C[M,N] = A[M,K] @ Bt[N,K]^T. D rows = n, cols = m. QKV: n0>=512 -> tile is V;
// result transposed through LDS, stored as full 128B lines into vout[(b,h,d)][t].
template<bool HASBIAS, bool RELU, int RES, bool OUT32, bool QKV>
__global__ __launch_bounds__(256) void gemm128(const u16* __restrict__ A,
                                               const u16* __restrict__ Bt,
                                               const float* __restrict__ bias,
                                               const void* __restrict__ resid,
                                               void* __restrict__ out,
                                               u16* __restrict__ vout,
                                               int M, int N, int K) {
    __shared__ __align__(16) u16 SH[17408];      // As|Bs (32KB) / V-transpose (34KB)
    u16* As = SH;
    u16* Bs = SH + 128 * 64;
    const int tid = threadIdx.x, lane = tid & 63, w = tid >> 6;
    const int m0 = blockIdx.x * 128, n0 = blockIdx.y * 128;
    const int wm = (w & 1) * 64, wn = (w >> 1) * 64;
    const int fm = lane & 15, q = lane >> 4;

    float4v acc[4][4];
    #pragma unroll
    for (int i = 0; i < 4; i++)
        #pragma unroll
        for (int j = 0; j < 4; j++) acc[i][j] = (float4v){0.f, 0.f, 0.f, 0.f};

    const int kset = ((lane & 7) ^ (lane >> 3)) * 8;
    const u16* Ag = A  + (size_t)(m0 + w * 32 + (lane >> 3)) * K + kset;
    const u16* Bg = Bt + (size_t)(n0 + w * 32 + (lane >> 3)) * K + kset;
    u16* Asw = As + (w * 32) * 64;
    u16* Bsw = Bs + (w * 32) * 64;

    const int sw = fm & 7;
    for (int k0 = 0; k0 < K; k0 += 64) {
        __syncthreads();
        #pragma unroll
        for (int c = 0; c < 4; c++) {
            async_cp16(Ag + (size_t)c * 8 * K + k0, Asw + c * 8 * 64);
            async_cp16(Bg + (size_t)c * 8 * K + k0, Bsw + c * 8 * 64);
        }
        __syncthreads();
        #pragma unroll
        for (int kk = 0; kk < 64; kk += 32) {
            const int slot = (((kk >> 3) + q) ^ sw) * 8;
            short8v af[4], bf[4];
            #pragma unroll
            for (int mi = 0; mi < 4; mi++)
                af[mi] = *(const short8v*)&As[(wm + mi * 16 + fm) * 64 + slot];
            #pragma unroll
            for (int ni = 0; ni < 4; ni++)
                bf[ni] = *(const short8v*)&Bs[(wn + ni * 16 + fm) * 64 + slot];
            #pragma unroll
            for (int mi = 0; mi < 4; mi++)
                #pragma unroll
                for (int ni = 0; ni < 4; ni++)
                    acc[mi][ni] = __builtin_amdgcn_mfma_f32_16x16x32_bf16(
                        bf[ni], af[mi], acc[mi][ni], 0, 0, 0);
        }
    }

    if (QKV && n0 >= 512) {
        // V tile: transpose via LDS, then coalesced full-line stores.
        __syncthreads();                          // all waves done with As/Bs
        #pragma unroll
        for (int mi = 0; mi < 4; mi++) {
            int ml = wm + mi * 16 + fm;           // t_local (col)
            #pragma unroll
            for (int ni = 0; ni < 4; ni++) {
                int nl = wn + ni * 16 + q * 4;    // d'_local (row)
                #pragma unroll
                for (int r = 0; r < 4; r++)
                    SH[(nl + r) * 136 + ml] = f2b(acc[mi][ni][r]);
            }
        }
        __syncthreads();
        int r = tid & 127, c = (tid >> 7) << 6;   // row d', 64-t chunk
        int hd = (n0 - 512) + r;
        int b = m0 >> 10, t0 = m0 & 1023;
        u16* dst = vout + (size_t)(b * 256 + hd) * 1024 + t0 + c;
        const u16* srcT = SH + r * 136 + c;
        #pragma unroll
        for (int i = 0; i < 8; i++)               // 8 x 16B = one 128B line/thread
            *(uint4*)(dst + i * 8) = *(const uint4*)(srcT + i * 8);
        return;
    }

    #pragma unroll
    for (int mi = 0; mi < 4; mi++) {
        int row = m0 + wm + mi * 16 + fm;
        #pragma unroll
        for (int ni = 0; ni < 4; ni++) {
            int nb = n0 + wn + ni * 16 + q * 4;
            float v0 = acc[mi][ni][0], v1 = acc[mi][ni][1],
                  v2 = acc[mi][ni][2], v3 = acc[mi][ni][3];
            if (HASBIAS) {
                float4 bv = *(const float4*)&bias[nb];
                v0 += bv.x; v1 += bv.y; v2 += bv.z; v3 += bv.w;
            }
            if (RELU) {
                v0 = fmaxf(v0, 0.f); v1 = fmaxf(v1, 0.f);
                v2 = fmaxf(v2, 0.f); v3 = fmaxf(v3, 0.f);
            }
            size_t idx = (size_t)row * N + nb;
            if (RES == 1) {
                uint2 rv = *(const uint2*)&((const u16*)resid)[idx];
                v0 += lo2f(rv.x); v1 += hi2f(rv.x);
                v2 += lo2f(rv.y); v3 += hi2f(rv.y);
            }
            if (OUT32) {
                *(float4*)&((float*)out)[idx] = (float4){v0, v1, v2, v3};
            } else {
                uint2 ov;
                ov.x = (u32)f2b(v0) | ((u32)f2b(v1) << 16);
                ov.y = (u32)f2b(v2) | ((u32)f2b(v3) << 16);
                *(uint2*)&((u16*)out)[idx] = ov;
            }
        }
    }
}

// ---------------- proj GEMM + residual + LN2 (r11, async staging) -----------
__global__ __launch_bounds__(256) void proj_ln2(const u16* __restrict__ att,
                                                const u16* __restrict__ wpT,
                                                const float* __restrict__ bp,
                                                const float* __restrict__ x,
                                                const float* __restrict__ g2,
                                                const float* __restrict__ be2,
                                                u16* __restrict__ x2b,
                                                u16* __restrict__ h2) {
    __shared__ __align__(16) u16 As[64 * 64];
    __shared__ __align__(16) u16 Bs[256 * 64];
    __shared__ float gs[256], bs[256], bps[256];
    const int tid = threadIdx.x, lane = tid & 63, w = tid >> 6;
    const int m0 = blockIdx.x * 64;
    const int fm = lane & 15, q = lane >> 4;

    gs[tid] = g2[tid]; bs[tid] = be2[tid]; bps[tid] = bp[tid];

    float4v acc[16];
    #pragma unroll
    for (int i = 0; i < 16; i++) acc[i] = (float4v){0.f, 0.f, 0.f, 0.f};

    const int kset = ((lane & 7) ^ (lane >> 3)) * 8;
    const u16* Ag = att + (size_t)(m0 + w * 16 + (lane >> 3)) * 256 + kset;
    const u16* Bg = wpT + (size_t)(w * 64 + (lane >> 3)) * 256 + kset;
    u16* Asw = As + (w * 16) * 64;
    u16* Bsw = Bs + (w * 64) * 64;

    const int sw = fm & 7;
    for (int k0 = 0; k0 < 256; k0 += 64) {
        __syncthreads();
        #pragma unroll
        for (int c = 0; c < 2; c++)
            async_cp16(Ag + (size_t)c * 8 * 256 + k0, Asw + c * 8 * 64);
        #pragma unroll
        for (int c = 0; c < 8; c++)
            async_cp16(Bg + (size_t)c * 8 * 256 + k0, Bsw + c * 8 * 64);
        __syncthreads();
        #pragma unroll
        for (int kk = 0; kk < 64; kk += 32) {
            const int slot = (((kk >> 3) + q) ^ sw) * 8;
            short8v af = *(const short8v*)&As[(w * 16 + fm) * 64 + slot];
            #pragma unroll
            for (int ni = 0; ni < 16; ni++) {
                short8v bf = *(const short8v*)&Bs[(ni * 16 + fm) * 64 + slot];
                acc[ni] = __builtin_amdgcn_mfma_f32_16x16x32_bf16(bf, af, acc[ni], 0, 0, 0);
            }
        }
    }

    int m = m0 + w * 16 + fm;
    float v[16][4];
    float s = 0.f, sq = 0.f;
    #pragma unroll
    for (int ni = 0; ni < 16; ni++) {
        int nb = ni * 16 + q * 4;
        float4 xv = *(const float4*)(x + (size_t)m * 256 + nb);
        float4 bv = *(const float4*)&bps[nb];
        #pragma unroll
        for (int r = 0; r < 4; r++) {
            float t = acc[ni][r] + (&bv.x)[r] + (&xv.x)[r];
            v[ni][r] = t;
            s += t; sq += t * t;
        }
    }
    s += __shfl_xor(s, 16);  s += __shfl_xor(s, 32);
    sq += __shfl_xor(sq, 16); sq += __shfl_xor(sq, 32);
    float mu = s * 0.00390625f;
    float rs = rsqrtf(sq * 0.00390625f - mu * mu + 1e-5f);
    #pragma unroll
    for (int ni = 0; ni < 16; ni++) {
        int nb = ni * 16 + q * 4;
        size_t idx = (size_t)m * 256 + nb;
        float4 gv = *(const float4*)&gs[nb];
        float4 bv = *(const float4*)&bs[nb];
        uint2 xo, ho;
        xo.x = (u32)f2b(v[ni][0]) | ((u32)f2b(v[ni][1]) << 16);
        xo.y = (u32)f2b(v[ni][2]) | ((u32)f2b(v[ni][3]) << 16);
        float h0 = (v[ni][0] - mu) * rs * gv.x + bv.x;
        float h1 = (v[ni][1] - mu) * rs * gv.y + bv.y;
        float h2v = (v[ni][2] - mu) * rs * gv.z + bv.z;
        float h3 = (v[ni][3] - mu) * rs * gv.w + bv.w;
        ho.x = (u32)f2b(h0) | ((u32)f2b(h1) << 16);
        ho.y = (u32)f2b(h2v) | ((u32)f2b(h3) << 16);
        *(uint2*)&x2b[idx] = xo;
        *(uint2*)&h2[idx] = ho;
    }
}

// ---------------- MFMA flash attention: single sweep, dual q-tile -----------
__global__ __launch_bounds__(256) void attn_mfma(const u16* __restrict__ qk,
                                                 const u16* __restrict__ vtg,
                                                 u16* __restrict__ att) {
    const int T = 1024;
    int jj = (blockIdx.x + (blockIdx.y >> 3)) & 7;
    int b = blockIdx.y >> 3, hh = blockIdx.y & 7;
    int tid = threadIdx.x;
    int lane = tid & 63, w = tid >> 6;
    int fm = lane & 15, q = lane >> 4;

    __shared__ __align__(16) u16 Ks[64][72];
    __shared__ __align__(16) u16 Vt[32][72];
    __shared__ __align__(16) u16 Pl[4][16][72];

    size_t base = (size_t)b * T * 512;
    const u16* kb = qk + base + 256 + hh * 32;
    const u16* vt = vtg + (size_t)((b * 8 + hh) * 32) * 1024;
    const int krow = tid >> 2, kcol = (tid & 3) * 8;
    const int vd = tid >> 3, vs = (tid & 7) * 8;

    int qa0 = jj * 64, qb0 = (15 - jj) * 64;
    int tqa = qa0 + w * 16 + fm, tqb = qb0 + w * 16 + fm;
    short8v qfa = *(const short8v*)(qk + base + (size_t)tqa * 512 + hh * 32 + q * 8);
    short8v qfb = *(const short8v*)(qk + base + (size_t)tqb * 512 + hh * 32 + q * 8);
    float4v oa0 = {0.f, 0.f, 0.f, 0.f}, oa1 = {0.f, 0.f, 0.f, 0.f};
    float4v ob0 = {0.f, 0.f, 0.f, 0.f}, ob1 = {0.f, 0.f, 0.f, 0.f};
    float la = 0.f, lb = 0.f;
    int wqa = qa0 + w * 16, wqb = qb0 + w * 16;
    int nIter = 16 - jj;

    uint4 kreg = *(const uint4*)(kb + (size_t)krow * 512 + kcol);
    uint4 vreg = *(const uint4*)(vt + (size_t)vd * 1024 + vs);

    for (int it = 0; it < nIter; ++it) {
        int s0 = it << 6;
        __syncthreads();
        *(uint4*)&Ks[krow][kcol] = kreg;
        *(uint4*)&Vt[vd][vs] = vreg;
        __syncthreads();
        if (it + 1 < nIter) {
            int ns0 = s0 + 64;
            kreg = *(const uint4*)(kb + (size_t)(ns0 + krow) * 512 + kcol);
            vreg = *(const uint4*)(vt + (size_t)vd * 1024 + ns0 + vs);
        }
        short8v kf0 = *(const short8v*)&Ks[fm][q * 8];
        short8v kf1 = *(const short8v*)&Ks[16 + fm][q * 8];
        short8v kf2 = *(const short8v*)&Ks[32 + fm][q * 8];
        short8v kf3 = *(const short8v*)&Ks[48 + fm][q * 8];
        short8v vf00 = *(const short8v*)&Vt[fm][q * 8];
        short8v vf01 = *(const short8v*)&Vt[fm][32 + q * 8];
        short8v vf10 = *(const short8v*)&Vt[16 + fm][q * 8];
        short8v vf11 = *(const short8v*)&Vt[16 + fm][32 + q * 8];
        float4v z = {0.f, 0.f, 0.f, 0.f};

        #pragma unroll
        for (int t2 = 0; t2 < 2; t2++) {       // t2=0: tile b (large), 1: tile a
            int wq0 = t2 ? wqa : wqb;
            if (s0 >= wq0 + 16) continue;      // wave-uniform causal skip
            int tq = t2 ? tqa : tqb;
            short8v qf = t2 ? qfa : qfb;
            float4v s_0 = __builtin_amdgcn_mfma_f32_16x16x32_bf16(kf0, qf, z, 0, 0, 0);
            float4v s_1 = __builtin_amdgcn_mfma_f32_16x16x32_bf16(kf1, qf, z, 0, 0, 0);
            float4v s_2 = __builtin_amdgcn_mfma_f32_16x16x32_bf16(kf2, qf, z, 0, 0, 0);
            float4v s_3 = __builtin_amdgcn_mfma_f32_16x16x32_bf16(kf3, qf, z, 0, 0, 0);
            float p[16];
            #pragma unroll
            for (int r = 0; r < 4; r++) {
                p[r] = exp2f(s_0[r]); p[4 + r] = exp2f(s_1[r]);
                p[8 + r] = exp2f(s_2[r]); p[12 + r] = exp2f(s_3[r]);
            }
            if (s0 + 63 > wq0) {               // diagonal region: causal mask
                int sb = s0 + q * 4;
                #pragma unroll
                for (int c = 0; c < 4; c++)
                    #pragma unroll
                    for (int r = 0; r < 4; r++)
                        if (sb + c * 16 + r > tq) p[c * 4 + r] = 0.f;
            }
            float rsum = 0.f;
            #pragma unroll
            for (int i = 0; i < 16; i++) rsum += p[i];
            rsum += __shfl_xor(rsum, 16);
            rsum += __shfl_xor(rsum, 32);
            if (t2) la += rsum; else lb += rsum;

            #pragma unroll
            for (int c = 0; c < 4; c++) {
                uint2 pp;
                pp.x = pk2_rtz(p[c * 4 + 0], p[c * 4 + 1]);
                pp.y = pk2_rtz(p[c * 4 + 2], p[c * 4 + 3]);
                *(uint2*)&Pl[w][fm][c * 16 + q * 4] = pp;   // wave-internal
            }
            short8v pf0 = *(const short8v*)&Pl[w][fm][q * 8];
            short8v pf1 = *(const short8v*)&Pl[w][fm][32 + q * 8];
            if (t2) {
                oa0 = __builtin_amdgcn_mfma_f32_16x16x32_bf16(vf00, pf0, oa0, 0, 0, 0);
                oa0 = __builtin_amdgcn_mfma_f32_16x16x32_bf16(vf01, pf1, oa0, 0, 0, 0);
                oa1 = __builtin_amdgcn_mfma_f32_16x16x32_bf16(vf10, pf0, oa1, 0, 0, 0);
                oa1 = __builtin_amdgcn_mfma_f32_16x16x32_bf16(vf11, pf1, oa1, 0, 0, 0);
            } else {
                ob0 = __builtin_amdgcn_mfma_f32_16x16x32_bf16(vf00, pf0, ob0, 0, 0, 0);
                ob0 = __builtin_amdgcn_mfma_f32_16x16x32_bf16(vf01, pf1, ob0, 0, 0, 0);
                ob1 = __builtin_amdgcn_mfma_f32_16x16x32_bf16(vf10, pf0, ob1, 0, 0, 0);
                ob1 = __builtin_amdgcn_mfma_f32_16x16x32_bf16(vf11, pf1, ob1, 0, 0, 0);
            }
        }
    }

    #pragma unroll
    for (int t2 = 0; t2 < 2; t2++) {
        float inv = 1.f / (t2 ? la : lb);
        float4v o0 = t2 ? oa0 : ob0, o1 = t2 ? oa1 : ob1;
        int tq = t2 ? tqa : tqb;
        uint2 r0, r1;
        r0.x = (u32)f2b(o0[0] * inv) | ((u32)f2b(o0[1] * inv) << 16);
        r0.y = (u32)f2b(o0[2] * inv) | ((u32)f2b(o0[3] * inv) << 16);
        r1.x = (u32)f2b(o1[0] * inv) | ((u32)f2b(o1[1] * inv) << 16);
        r1.y = (u32)f2b(o1[2] * inv) | ((u32)f2b(o1[3] * inv) << 16);
        size_t o = (size_t)(b * T + tq) * 256 + hh * 32;
        *(uint2*)(att + o + q * 4) = r0;
        *(uint2*)(att + o + 16 + q * 4) = r1;
    }
}

// ---------------- launch ----------------
extern "C" void kernel_launch(void* const* d_in, const int* in_sizes, int n_in,
                              void* d_out, int out_size, void* d_ws, size_t ws_size,
                              hipStream_t stream) {
    const int BT = 16 * 1024;
    const float* x      = (const float*)d_in[0];
    const float* wq     = (const float*)d_in[1];
    const float* wk     = (const float*)d_in[2];
    const float* wv     = (const float*)d_in[3];
    const float* w_proj = (const float*)d_in[4];
    const float* b_proj = (const float*)d_in[5];
    const float* w1     = (const float*)d_in[6];
    const float* b1     = (const float*)d_in[7];
    const float* w2     = (const float*)d_in[8];
    const float* b2     = (const float*)d_in[9];
    const float* ln1_g  = (const float*)d_in[10];
    const float* ln1_b  = (const float*)d_in[11];
    const float* ln2_g  = (const float*)d_in[12];
    const float* ln2_b  = (const float*)d_in[13];

    // Workspace (~49.5 MiB):
    //   [0, 8M)   x2b (bf16 x2)
    //   [8M,16M)  hbuf: h -> att -> h2  [serial, proj_ln2 in-place]
    //   [16M,32M) qk [BT,512] | [32M,48M) vtg  -> dead after attn
    //   [16M,48M) mid (born after attn)
    //   [48M...)  packed weights (1.5M)
    char* ws = (char*)d_ws;
    const size_t MB = 1024 * 1024;
    u16*  x2b   = (u16*)(ws + 0);
    u16*  hbuf  = (u16*)(ws + 8 * MB);
    u16*  qk    = (u16*)(ws + 16 * MB);
    u16*  vtg   = (u16*)(ws + 32 * MB);
    u16*  mid   = (u16*)(ws + 16 * MB);
    u16*  wqkvT = (u16*)(ws + 48 * MB);
    u16*  wpT   = (u16*)(ws + 48 * MB + 0x60000);
    u16*  w1T   = (u16*)(ws + 48 * MB + 0x80000);
    u16*  w2T   = (u16*)(ws + 48 * MB + 0x100000);

    prep_ln1<<<5008, 256, 0, stream>>>(wq, wk, wv, w_proj, w1, w2, x, ln1_g, ln1_b,
                                       wqkvT, wpT, w1T, w2T, hbuf);
    gemm128<false, false, 0, false, true><<<dim3(128, 6), 256, 0, stream>>>(
        hbuf, wqkvT, nullptr, nullptr, qk, vtg, BT, 512, 256);
    attn_mfma<<<dim3(8, 128), 256, 0, stream>>>(qk, vtg, hbuf);
    proj_ln2<<<256, 256, 0, stream>>>(hbuf, wpT, b_proj, x, ln2_g, ln2_b, x2b, hbuf);
    gemm128<true, true, 0, false, false><<<dim3(128, 8), 256, 0, stream>>>(
        hbuf, w1T, b1, nullptr, mid, nullptr, BT, 1024, 256);
    gemm128<true, false, 1, true, false><<<dim3(128, 2), 256, 0, stream>>>(
        mid, w2T, b2, x2b, d_out, nullptr, BT, 256, 1024);
}

// Round 14
// 194.830 us; speedup vs baseline: 1.5838x; 1.0165x over previous
//
#include <hip/hip_runtime.h>

// EncoderBlock on MI355X. Round 14: 2-blocks/CU for the two 1-block/CU kernels —
// ffn2 as 64x128-tile gemm64 (grid 512), proj_ln2 as 32-row blocks (grid 512,
// cross-wave LN reduce). Everything else identical to r13 (198 µs best).
// 6 launches. Inputs fp32 storage, d_out fp32. B=16 T=1024 C=256 H=8 D=32.

typedef unsigned short u16;
typedef unsigned int u32;
typedef __attribute__((ext_vector_type(8))) short short8v;  // 8 bf16 MFMA A/B frag
typedef __attribute__((ext_vector_type(4))) float float4v;  // MFMA C/D frag

__device__ __forceinline__ float b2f(u16 u) { union { u32 i; float f; } v; v.i = (u32)u << 16; return v.f; }
__device__ __forceinline__ float lo2f(u32 u) { union { u32 i; float f; } v; v.i = u << 16; return v.f; }
__device__ __forceinline__ float hi2f(u32 u) { union { u32 i; float f; } v; v.i = u & 0xffff0000u; return v.f; }
__device__ __forceinline__ u16 f2b(float f) {
    union { float f; u32 i; } v; v.f = f;
    u32 r = v.i + 0x7fffu + ((v.i >> 16) & 1u);  // RTNE
    return (u16)(r >> 16);
}
__device__ __forceinline__ u32 pk2_rtz(float a, float b) {
    return (__float_as_uint(a) >> 16) | (__float_as_uint(b) & 0xffff0000u);
}
__device__ __forceinline__ void async_cp16(const u16* g, u16* l) {
    __builtin_amdgcn_global_load_lds((const __attribute__((address_space(1))) void*)g,
                                     (__attribute__((address_space(3))) void*)l, 16, 0, 0);
}

// ---------------- fused prep (wqkv pack + 3 transposes) + LN1 ---------------
__global__ __launch_bounds__(256) void prep_ln1(const float* __restrict__ wq,
                                                const float* __restrict__ wk,
                                                const float* __restrict__ wv,
                                                const float* __restrict__ wp,
                                                const float* __restrict__ w1,
                                                const float* __restrict__ w2,
                                                const float* __restrict__ x,
                                                const float* __restrict__ g1,
                                                const float* __restrict__ be1,
                                                u16* __restrict__ wqkvT,
                                                u16* __restrict__ wpT,
                                                u16* __restrict__ w1T,
                                                u16* __restrict__ w2T,
                                                u16* __restrict__ hout) {
    __shared__ u16 tile[64][65];
    int bid = blockIdx.x, tid = threadIdx.x;
    if (bid < 768) {
        int i = bid * 256 + tid;
        int n = i >> 8, k = i & 255;
        int which = n >> 8, nn = n & 255;
        const float* w = which == 0 ? wq : (which == 1 ? wk : wv);
        float v = w[((nn >> 5) * 256 + k) * 32 + (nn & 31)];   // w[h][k][d]
        if (which == 0) v *= 0.09016844f;                      // (1/16)*log2(e)
        wqkvT[i] = f2b(v);
    } else if (bid < 912) {
        const float* src; u16* dst; int K, N, t;
        if (bid < 784)      { src = wp; dst = wpT; K = 256;  N = 256;  t = bid - 768; }
        else if (bid < 848) { src = w1; dst = w1T; K = 256;  N = 1024; t = bid - 784; }
        else                { src = w2; dst = w2T; K = 1024; N = 256;  t = bid - 848; }
        int ntn = N >> 6;
        int k0 = (t / ntn) << 6, n0 = (t % ntn) << 6;
        int lane = tid & 63, wrow = tid >> 6;
        #pragma unroll
        for (int r = 0; r < 16; r++) {
            int k = wrow * 16 + r;
            tile[k][lane] = f2b(src[(size_t)(k0 + k) * N + n0 + lane]);
        }
        __syncthreads();
        #pragma unroll
        for (int r = 0; r < 16; r++) {
            int n = wrow * 16 + r;
            dst[(size_t)(n0 + n) * K + k0 + lane] = tile[lane][n];
        }
    } else {
        int row = (bid - 912) * 4 + (tid >> 6);
        int lane = tid & 63;
        float4 xv = *(const float4*)(x + (size_t)row * 256 + lane * 4);
        float v0 = xv.x, v1 = xv.y, v2 = xv.z, v3 = xv.w;
        float s = v0 + v1 + v2 + v3;
        #pragma unroll
        for (int m = 32; m; m >>= 1) s += __shfl_xor(s, m);
        float mu = s * 0.00390625f;
        float d0 = v0 - mu, d1 = v1 - mu, d2 = v2 - mu, d3 = v3 - mu;
        float ss = d0 * d0 + d1 * d1 + d2 * d2 + d3 * d3;
        #pragma unroll
        for (int m = 32; m; m >>= 1) ss += __shfl_xor(ss, m);
        float rs = rsqrtf(ss * 0.00390625f + 1e-5f);
        float4 g = *(const float4*)(g1 + lane * 4);
        float4 b = *(const float4*)(be1 + lane * 4);
        uint2 r;
        r.x = (u32)f2b(d0 * rs * g.x + b.x) | ((u32)f2b(d1 * rs * g.y + b.y) << 16);
        r.y = (u32)f2b(d2 * rs * g.z + b.z) | ((u32)f2b(d3 * rs * g.w + b.w) << 16);
        *(uint2*)(hout + (size_t)row * 256 + lane * 4) = r;
    }
}

// ---------------- 128x128 MFMA GEMM (qkv / ffn1), async + LDS V-transpose ---
template<bool HASBIAS, bool RELU, bool QKV>
__global__ __launch_bounds__(256) void gemm128(const u16* __restrict__ A,
                                               const u16* __restrict__ Bt,
                                               const float* __restrict__ bias,
                                               u16* __restrict__ out,
                                               u16* __restrict__ vout,
                                               int M, int N, int K) {
    __shared__ __align__(16) u16 SH[17408];      // As|Bs (32KB) / V-transpose (34KB)
    u16* As = SH;
    u16* Bs = SH + 128 * 64;
    const int tid = threadIdx.x, lane = tid & 63, w = tid >> 6;
    const int m0 = blockIdx.x * 128, n0 = blockIdx.y * 128;
    const int wm = (w & 1) * 64, wn = (w >> 1) * 64;
    const int fm = lane & 15, q = lane >> 4;

    float4v acc[4][4];
    #pragma unroll
    for (int i = 0; i < 4; i++)
        #pragma unroll
        for (int j = 0; j < 4; j++) acc[i][j] = (float4v){0.f, 0.f, 0.f, 0.f};

    const int kset = ((lane & 7) ^ (lane >> 3)) * 8;
    const u16* Ag = A  + (size_t)(m0 + w * 32 + (lane >> 3)) * K + kset;
    const u16* Bg = Bt + (size_t)(n0 + w * 32 + (lane >> 3)) * K + kset;
    u16* Asw = As + (w * 32) * 64;
    u16* Bsw = Bs + (w * 32) * 64;

    const int sw = fm & 7;
    for (int k0 = 0; k0 < K; k0 += 64) {
        __syncthreads();
        #pragma unroll
        for (int c = 0; c < 4; c++) {
            async_cp16(Ag + (size_t)c * 8 * K + k0, Asw + c * 8 * 64);
            async_cp16(Bg + (size_t)c * 8 * K + k0, Bsw + c * 8 * 64);
        }
        __syncthreads();
        #pragma unroll
        for (int kk = 0; kk < 64; kk += 32) {
            const int slot = (((kk >> 3) + q) ^ sw) * 8;
            short8v af[4], bf[4];
            #pragma unroll
            for (int mi = 0; mi < 4; mi++)
                af[mi] = *(const short8v*)&As[(wm + mi * 16 + fm) * 64 + slot];
            #pragma unroll
            for (int ni = 0; ni < 4; ni++)
                bf[ni] = *(const short8v*)&Bs[(wn + ni * 16 + fm) * 64 + slot];
            #pragma unroll
            for (int mi = 0; mi < 4; mi++)
                #pragma unroll
                for (int ni = 0; ni < 4; ni++)
                    acc[mi][ni] = __builtin_amdgcn_mfma_f32_16x16x32_bf16(
                        bf[ni], af[mi], acc[mi][ni], 0, 0, 0);
        }
    }

    if (QKV && n0 >= 512) {
        // V tile: transpose via LDS, then coalesced full-line stores.
        __syncthreads();
        #pragma unroll
        for (int mi = 0; mi < 4; mi++) {
            int ml = wm + mi * 16 + fm;
            #pragma unroll
            for (int ni = 0; ni < 4; ni++) {
                int nl = wn + ni * 16 + q * 4;
                #pragma unroll
                for (int r = 0; r < 4; r++)
                    SH[(nl + r) * 136 + ml] = f2b(acc[mi][ni][r]);
            }
        }
        __syncthreads();
        int r = tid & 127, c = (tid >> 7) << 6;
        int hd = (n0 - 512) + r;
        int b = m0 >> 10, t0 = m0 & 1023;
        u16* dst = vout + (size_t)(b * 256 + hd) * 1024 + t0 + c;
        const u16* srcT = SH + r * 136 + c;
        #pragma unroll
        for (int i = 0; i < 8; i++)
            *(uint4*)(dst + i * 8) = *(const uint4*)(srcT + i * 8);
        return;
    }

    #pragma unroll
    for (int mi = 0; mi < 4; mi++) {
        int row = m0 + wm + mi * 16 + fm;
        #pragma unroll
        for (int ni = 0; ni < 4; ni++) {
            int nb = n0 + wn + ni * 16 + q * 4;
            float v0 = acc[mi][ni][0], v1 = acc[mi][ni][1],
                  v2 = acc[mi][ni][2], v3 = acc[mi][ni][3];
            if (HASBIAS) {
                float4 bv = *(const float4*)&bias[nb];
                v0 += bv.x; v1 += bv.y; v2 += bv.z; v3 += bv.w;
            }
            if (RELU) {
                v0 = fmaxf(v0, 0.f); v1 = fmaxf(v1, 0.f);
                v2 = fmaxf(v2, 0.f); v3 = fmaxf(v3, 0.f);
            }
            size_t idx = (size_t)row * N + nb;
            uint2 ov;
            ov.x = (u32)f2b(v0) | ((u32)f2b(v1) << 16);
            ov.y = (u32)f2b(v2) | ((u32)f2b(v3) << 16);
            *(uint2*)&out[idx] = ov;
        }
    }
}

// ---------------- 64x128 MFMA GEMM (ffn2): 2 blocks/CU ----------------------
// out = A[M,K] @ Bt[N,K]^T + bias + resid(bf16), fp32 stores. Waves 2x2 of
// 32m x 64n (2x4 frags). grid (M/64, N/128).
__global__ __launch_bounds__(256) void gemm64(const u16* __restrict__ A,
                                              const u16* __restrict__ Bt,
                                              const float* __restrict__ bias,
                                              const u16* __restrict__ resid,
                                              float* __restrict__ out,
                                              int M, int N, int K) {
    __shared__ __align__(16) u16 As[64 * 64];
    __shared__ __align__(16) u16 Bs[128 * 64];
    const int tid = threadIdx.x, lane = tid & 63, w = tid >> 6;
    const int m0 = blockIdx.x * 64, n0 = blockIdx.y * 128;
    const int wm = (w & 1) * 32, wn = (w >> 1) * 64;
    const int fm = lane & 15, q = lane >> 4;

    float4v acc[2][4];
    #pragma unroll
    for (int i = 0; i < 2; i++)
        #pragma unroll
        for (int j = 0; j < 4; j++) acc[i][j] = (float4v){0.f, 0.f, 0.f, 0.f};

    const int kset = ((lane & 7) ^ (lane >> 3)) * 8;
    const u16* Ag = A  + (size_t)(m0 + w * 16 + (lane >> 3)) * K + kset;
    const u16* Bg = Bt + (size_t)(n0 + w * 32 + (lane >> 3)) * K + kset;
    u16* Asw = As + (w * 16) * 64;
    u16* Bsw = Bs + (w * 32) * 64;

    const int sw = fm & 7;
    for (int k0 = 0; k0 < K; k0 += 64) {
        __syncthreads();
        #pragma unroll
        for (int c = 0; c < 2; c++)
            async_cp16(Ag + (size_t)c * 8 * K + k0, Asw + c * 8 * 64);
        #pragma unroll
        for (int c = 0; c < 4; c++)
            async_cp16(Bg + (size_t)c * 8 * K + k0, Bsw + c * 8 * 64);
        __syncthreads();
        #pragma unroll
        for (int kk = 0; kk < 64; kk += 32) {
            const int slot = (((kk >> 3) + q) ^ sw) * 8;
            short8v af[2], bf[4];
            #pragma unroll
            for (int mi = 0; mi < 2; mi++)
                af[mi] = *(const short8v*)&As[(wm + mi * 16 + fm) * 64 + slot];
            #pragma unroll
            for (int ni = 0; ni < 4; ni++)
                bf[ni] = *(const short8v*)&Bs[(wn + ni * 16 + fm) * 64 + slot];
            #pragma unroll
            for (int mi = 0; mi < 2; mi++)
                #pragma unroll
                for (int ni = 0; ni < 4; ni++)
                    acc[mi][ni] = __builtin_amdgcn_mfma_f32_16x16x32_bf16(
                        bf[ni], af[mi], acc[mi][ni], 0, 0, 0);
        }
    }

    #pragma unroll
    for (int mi = 0; mi < 2; mi++) {
        int row = m0 + wm + mi * 16 + fm;
        #pragma unroll
        for (int ni = 0; ni < 4; ni++) {
            int nb = n0 + wn + ni * 16 + q * 4;
            size_t idx = (size_t)row * N + nb;
            float4 bv = *(const float4*)&bias[nb];
            uint2 rv = *(const uint2*)&resid[idx];
            float v0 = acc[mi][ni][0] + bv.x + lo2f(rv.x);
            float v1 = acc[mi][ni][1] + bv.y + hi2f(rv.x);
            float v2 = acc[mi][ni][2] + bv.z + lo2f(rv.y);
            float v3 = acc[mi][ni][3] + bv.w + hi2f(rv.y);
            *(float4*)&out[idx] = (float4){v0, v1, v2, v3};
        }
    }
}

// ---------------- proj GEMM + residual + LN2: 32-row blocks, 2/CU -----------
// x2 = att @ wpT^T + bp + x ; h2 = LN2(x2). grid 512. Waves: 2 x (16m x 128n),
// frags 1x8. Row stats: quad shuffles (own 128 ch) + LDS exchange with wave^2.
__global__ __launch_bounds__(256) void proj_ln2(const u16* __restrict__ att,
                                                const u16* __restrict__ wpT,
                                                const float* __restrict__ bp,
                                                const float* __restrict__ x,
                                                const float* __restrict__ g2,
                                                const float* __restrict__ be2,
                                                u16* __restrict__ x2b,
                                                u16* __restrict__ h2) {
    __shared__ __align__(16) u16 As[32 * 64];
    __shared__ __align__(16) u16 Bs[256 * 64];
    __shared__ float gs[256], bs[256], bps[256];
    __shared__ float ps[4][16], pq[4][16];
    const int tid = threadIdx.x, lane = tid & 63, w = tid >> 6;
    const int m0 = blockIdx.x * 32;
    const int wm = (w & 1) * 16, wn = (w >> 1) * 128;
    const int fm = lane & 15, q = lane >> 4;

    gs[tid] = g2[tid]; bs[tid] = be2[tid]; bps[tid] = bp[tid];

    float4v acc[8];
    #pragma unroll
    for (int i = 0; i < 8; i++) acc[i] = (float4v){0.f, 0.f, 0.f, 0.f};

    const int kset = ((lane & 7) ^ (lane >> 3)) * 8;
    const u16* Ag = att + (size_t)(m0 + w * 8 + (lane >> 3)) * 256 + kset;
    const u16* Bg = wpT + (size_t)(w * 64 + (lane >> 3)) * 256 + kset;
    u16* Asw = As + (w * 8) * 64;
    u16* Bsw = Bs + (w * 64) * 64;

    const int sw = fm & 7;
    for (int k0 = 0; k0 < 256; k0 += 64) {
        __syncthreads();
        async_cp16(Ag + k0, Asw);
        #pragma unroll
        for (int c = 0; c < 8; c++)
            async_cp16(Bg + (size_t)c * 8 * 256 + k0, Bsw + c * 8 * 64);
        __syncthreads();
        #pragma unroll
        for (int kk = 0; kk < 64; kk += 32) {
            const int slot = (((kk >> 3) + q) ^ sw) * 8;
            short8v af = *(const short8v*)&As[(wm + fm) * 64 + slot];
            #pragma unroll
            for (int ni = 0; ni < 8; ni++) {
                short8v bf = *(const short8v*)&Bs[(wn + ni * 16 + fm) * 64 + slot];
                acc[ni] = __builtin_amdgcn_mfma_f32_16x16x32_bf16(bf, af, acc[ni], 0, 0, 0);
            }
        }
    }

    // epilogue: row m = m0+wm+fm; thread covers 32 of its 256 channels
    int m = m0 + wm + fm;
    float v[8][4];
    float s = 0.f, sq = 0.f;
    #pragma unroll
    for (int ni = 0; ni < 8; ni++) {
        int nb = wn + ni * 16 + q * 4;
        float4 xv = *(const float4*)(x + (size_t)m * 256 + nb);
        float4 bv = *(const float4*)&bps[nb];
        #pragma unroll
        for (int r = 0; r < 4; r++) {
            float t = acc[ni][r] + (&bv.x)[r] + (&xv.x)[r];
            v[ni][r] = t;
            s += t; sq += t * t;
        }
    }
    s += __shfl_xor(s, 16);  s += __shfl_xor(s, 32);   // sum over q -> 128 ch
    sq += __shfl_xor(sq, 16); sq += __shfl_xor(sq, 32);
    if (q == 0) { ps[w][fm] = s; pq[w][fm] = sq; }
    __syncthreads();
    s = ps[w][fm] + ps[w ^ 2][fm];                      // + partner wave's 128 ch
    sq = pq[w][fm] + pq[w ^ 2][fm];
    float mu = s * 0.00390625f;
    float rs = rsqrtf(sq * 0.00390625f - mu * mu + 1e-5f);
    #pragma unroll
    for (int ni = 0; ni < 8; ni++) {
        int nb = wn + ni * 16 + q * 4;
        size_t idx = (size_t)m * 256 + nb;
        float4 gv = *(const float4*)&gs[nb];
        float4 bv = *(const float4*)&bs[nb];
        uint2 xo, ho;
        xo.x = (u32)f2b(v[ni][0]) | ((u32)f2b(v[ni][1]) << 16);
        xo.y = (u32)f2b(v[ni][2]) | ((u32)f2b(v[ni][3]) << 16);
        float h0 = (v[ni][0] - mu) * rs * gv.x + bv.x;
        float h1 = (v[ni][1] - mu) * rs * gv.y + bv.y;
        float h2v = (v[ni][2] - mu) * rs * gv.z + bv.z;
        float h3 = (v[ni][3] - mu) * rs * gv.w + bv.w;
        ho.x = (u32)f2b(h0) | ((u32)f2b(h1) << 16);
        ho.y = (u32)f2b(h2v) | ((u32)f2b(h3) << 16);
        *(uint2*)&x2b[idx] = xo;
        *(uint2*)&h2[idx] = ho;    // in-place over att: own rows, post-k-loop
    }
}

// ---------------- MFMA flash attention: single sweep, dual q-tile -----------
__global__ __launch_bounds__(256) void attn_mfma(const u16* __restrict__ qk,
                                                 const u16* __restrict__ vtg,
                                                 u16* __restrict__ att) {
    const int T = 1024;
    int jj = (blockIdx.x + (blockIdx.y >> 3)) & 7;
    int b = blockIdx.y >> 3, hh = blockIdx.y & 7;
    int tid = threadIdx.x;
    int lane = tid & 63, w = tid >> 6;
    int fm = lane & 15, q = lane >> 4;

    __shared__ __align__(16) u16 Ks[64][72];
    __shared__ __align__(16) u16 Vt[32][72];
    __shared__ __align__(16) u16 Pl[4][16][72];

    size_t base = (size_t)b * T * 512;
    const u16* kb = qk + base + 256 + hh * 32;
    const u16* vt = vtg + (size_t)((b * 8 + hh) * 32) * 1024;
    const int krow = tid >> 2, kcol = (tid & 3) * 8;
    const int vd = tid >> 3, vs = (tid & 7) * 8;

    int qa0 = jj * 64, qb0 = (15 - jj) * 64;
    int tqa = qa0 + w * 16 + fm, tqb = qb0 + w * 16 + fm;
    short8v qfa = *(const short8v*)(qk + base + (size_t)tqa * 512 + hh * 32 + q * 8);
    short8v qfb = *(const short8v*)(qk + base + (size_t)tqb * 512 + hh * 32 + q * 8);
    float4v oa0 = {0.f, 0.f, 0.f, 0.f}, oa1 = {0.f, 0.f, 0.f, 0.f};
    float4v ob0 = {0.f, 0.f, 0.f, 0.f}, ob1 = {0.f, 0.f, 0.f, 0.f};
    float la = 0.f, lb = 0.f;
    int wqa = qa0 + w * 16, wqb = qb0 + w * 16;
    int nIter = 16 - jj;

    uint4 kreg = *(const uint4*)(kb + (size_t)krow * 512 + kcol);
    uint4 vreg = *(const uint4*)(vt + (size_t)vd * 1024 + vs);

    for (int it = 0; it < nIter; ++it) {
        int s0 = it << 6;
        __syncthreads();
        *(uint4*)&Ks[krow][kcol] = kreg;
        *(uint4*)&Vt[vd][vs] = vreg;
        __syncthreads();
        if (it + 1 < nIter) {
            int ns0 = s0 + 64;
            kreg = *(const uint4*)(kb + (size_t)(ns0 + krow) * 512 + kcol);
            vreg = *(const uint4*)(vt + (size_t)vd * 1024 + ns0 + vs);
        }
        short8v kf0 = *(const short8v*)&Ks[fm][q * 8];
        short8v kf1 = *(const short8v*)&Ks[16 + fm][q * 8];
        short8v kf2 = *(const short8v*)&Ks[32 + fm][q * 8];
        short8v kf3 = *(const short8v*)&Ks[48 + fm][q * 8];
        short8v vf00 = *(const short8v*)&Vt[fm][q * 8];
        short8v vf01 = *(const short8v*)&Vt[fm][32 + q * 8];
        short8v vf10 = *(const short8v*)&Vt[16 + fm][q * 8];
        short8v vf11 = *(const short8v*)&Vt[16 + fm][32 + q * 8];
        float4v z = {0.f, 0.f, 0.f, 0.f};

        #pragma unroll
        for (int t2 = 0; t2 < 2; t2++) {       // t2=0: tile b (large), 1: tile a
            int wq0 = t2 ? wqa : wqb;
            if (s0 >= wq0 + 16) continue;      // wave-uniform causal skip
            int tq = t2 ? tqa : tqb;
            short8v qf = t2 ? qfa : qfb;
            float4v s_0 = __builtin_amdgcn_mfma_f32_16x16x32_bf16(kf0, qf, z, 0, 0, 0);
            float4v s_1 = __builtin_amdgcn_mfma_f32_16x16x32_bf16(kf1, qf, z, 0, 0, 0);
            float4v s_2 = __builtin_amdgcn_mfma_f32_16x16x32_bf16(kf2, qf, z, 0, 0, 0);
            float4v s_3 = __builtin_amdgcn_mfma_f32_16x16x32_bf16(kf3, qf, z, 0, 0, 0);
            float p[16];
            #pragma unroll
            for (int r = 0; r < 4; r++) {
                p[r] = exp2f(s_0[r]); p[4 + r] = exp2f(s_1[r]);
                p[8 + r] = exp2f(s_2[r]); p[12 + r] = exp2f(s_3[r]);
            }
            if (s0 + 63 > wq0) {               // diagonal region: causal mask
                int sb = s0 + q * 4;
                #pragma unroll
                for (int c = 0; c < 4; c++)
                    #pragma unroll
                    for (int r = 0; r < 4; r++)
                        if (sb + c * 16 + r > tq) p[c * 4 + r] = 0.f;
            }
            float rsum = 0.f;
            #pragma unroll
            for (int i = 0; i < 16; i++) rsum += p[i];
            rsum += __shfl_xor(rsum, 16);
            rsum += __shfl_xor(rsum, 32);
            if (t2) la += rsum; else lb += rsum;

            #pragma unroll
            for (int c = 0; c < 4; c++) {
                uint2 pp;
                pp.x = pk2_rtz(p[c * 4 + 0], p[c * 4 + 1]);
                pp.y = pk2_rtz(p[c * 4 + 2], p[c * 4 + 3]);
                *(uint2*)&Pl[w][fm][c * 16 + q * 4] = pp;   // wave-internal
            }
            short8v pf0 = *(const short8v*)&Pl[w][fm][q * 8];
            short8v pf1 = *(const short8v*)&Pl[w][fm][32 + q * 8];
            if (t2) {
                oa0 = __builtin_amdgcn_mfma_f32_16x16x32_bf16(vf00, pf0, oa0, 0, 0, 0);
                oa0 = __builtin_amdgcn_mfma_f32_16x16x32_bf16(vf01, pf1, oa0, 0, 0, 0);
                oa1 = __builtin_amdgcn_mfma_f32_16x16x32_bf16(vf10, pf0, oa1, 0, 0, 0);
                oa1 = __builtin_amdgcn_mfma_f32_16x16x32_bf16(vf11, pf1, oa1, 0, 0, 0);
            } else {
                ob0 = __builtin_amdgcn_mfma_f32_16x16x32_bf16(vf00, pf0, ob0, 0, 0, 0);
                ob0 = __builtin_amdgcn_mfma_f32_16x16x32_bf16(vf01, pf1, ob0, 0, 0, 0);
                ob1 = __builtin_amdgcn_mfma_f32_16x16x32_bf16(vf10, pf0, ob1, 0, 0, 0);
                ob1 = __builtin_amdgcn_mfma_f32_16x16x32_bf16(vf11, pf1, ob1, 0, 0, 0);
            }
        }
    }

    #pragma unroll
    for (int t2 = 0; t2 < 2; t2++) {
        float inv = 1.f / (t2 ? la : lb);
        float4v o0 = t2 ? oa0 : ob0, o1 = t2 ? oa1 : ob1;
        int tq = t2 ? tqa : tqb;
        uint2 r0, r1;
        r0.x = (u32)f2b(o0[0] * inv) | ((u32)f2b(o0[1] * inv) << 16);
        r0.y = (u32)f2b(o0[2] * inv) | ((u32)f2b(o0[3] * inv) << 16);
        r1.x = (u32)f2b(o1[0] * inv) | ((u32)f2b(o1[1] * inv) << 16);
        r1.y = (u32)f2b(o1[2] * inv) | ((u32)f2b(o1[3] * inv) << 16);
        size_t o = (size_t)(b * T + tq) * 256 + hh * 32;
        *(uint2*)(att + o + q * 4) = r0;
        *(uint2*)(att + o + 16 + q * 4) = r1;
    }
}

// ---------------- launch ----------------
extern "C" void kernel_launch(void* const* d_in, const int* in_sizes, int n_in,
                              void* d_out, int out_size, void* d_ws, size_t ws_size,
                              hipStream_t stream) {
    const int BT = 16 * 1024;
    const float* x      = (const float*)d_in[0];
    const float* wq     = (const float*)d_in[1];
    const float* wk     = (const float*)d_in[2];
    const float* wv     = (const float*)d_in[3];
    const float* w_proj = (const float*)d_in[4];
    const float* b_proj = (const float*)d_in[5];
    const float* w1     = (const float*)d_in[6];
    const float* b1     = (const float*)d_in[7];
    const float* w2     = (const float*)d_in[8];
    const float* b2     = (const float*)d_in[9];
    const float* ln1_g  = (const float*)d_in[10];
    const float* ln1_b  = (const float*)d_in[11];
    const float* ln2_g  = (const float*)d_in[12];
    const float* ln2_b  = (const float*)d_in[13];

    // Workspace (~49.5 MiB):
    //   [0, 8M)   x2b (bf16 x2)
    //   [8M,16M)  hbuf: h -> att -> h2  [serial, proj_ln2 in-place]
    //   [16M,32M) qk [BT,512] | [32M,48M) vtg  -> dead after attn
    //   [16M,48M) mid (born after attn)
    //   [48M...)  packed weights (1.5M)
    char* ws = (char*)d_ws;
    const size_t MB = 1024 * 1024;
    u16*  x2b   = (u16*)(ws + 0);
    u16*  hbuf  = (u16*)(ws + 8 * MB);
    u16*  qk    = (u16*)(ws + 16 * MB);
    u16*  vtg   = (u16*)(ws + 32 * MB);
    u16*  mid   = (u16*)(ws + 16 * MB);
    u16*  wqkvT = (u16*)(ws + 48 * MB);
    u16*  wpT   = (u16*)(ws + 48 * MB + 0x60000);
    u16*  w1T   = (u16*)(ws + 48 * MB + 0x80000);
    u16*  w2T   = (u16*)(ws + 48 * MB + 0x100000);

    prep_ln1<<<5008, 256, 0, stream>>>(wq, wk, wv, w_proj, w1, w2, x, ln1_g, ln1_b,
                                       wqkvT, wpT, w1T, w2T, hbuf);
    // qk | vtg = h @ [Wq'|Wk|Wv]
    gemm128<false, false, true><<<dim3(128, 6), 256, 0, stream>>>(
        hbuf, wqkvT, nullptr, qk, vtg, BT, 512, 256);
    // att = flash attention (writes over h)
    attn_mfma<<<dim3(8, 128), 256, 0, stream>>>(qk, vtg, hbuf);
    // x2 = x + att @ w_proj + b_proj ; h2 = LN2(x2)  [32-row blocks, 2/CU]
    proj_ln2<<<512, 256, 0, stream>>>(hbuf, wpT, b_proj, x, ln2_g, ln2_b, x2b, hbuf);
    // mid = relu(h2 @ w1 + b1)
    gemm128<true, true, false><<<dim3(128, 8), 256, 0, stream>>>(
        hbuf, w1T, b1, mid, nullptr, BT, 1024, 256);
    // out = x2 + mid @ w2 + b2  [64x128 tiles, 2/CU]
    gemm64<<<dim3(256, 2), 256, 0, stream>>>(
        mid, w2T, b2, x2b, (float*)d_out, BT, 256, 1024);
}